// Round 5
// baseline (273.829 us; speedup 1.0000x reference)
//
#include <hip/hip_runtime.h>
#include <hip/hip_bf16.h>

// LightGCN on MI355X. R17: mid-pipeline harvest (bsort LDS-stage, BP=512,
// list-compacted l2, 64x64 gemm).
// R16 post-mortem: fusion 13->8 dispatches = -13.4 us (~2.7 us/dispatch).
// l1fuse 42.2 us, FETCH 120 MB, occ 64% -- at the per-XCD unique-line
// gather floor (R14 model ~124 MB; R15 occupancy-invariance proof). DONE.
// Remaining budget: bsort ~25 / p2 ~20 / l2fuse ~18 / init_p1 ~15 /
// gemm ~10 / scanA ~5 + 41.6 us harness ws-poison fill (untouchable).
// R17: (1) bsort stages bucket edges in LDS once (saves 18 MB part
//          re-read); CAP 8192->7680 so ed 60KB+st 2KB < 64KB static cap
//          (mean 6827, sd 82 -> +10.3 sigma); 293 blocks ~1.1/CU so LDS
//          costs no occupancy.
//      (2) BP 2048->512: scanA 4x smaller; p2 runs 4x longer (~107 B) ->
//          write-amp ~1.33 -> ~1.1; blockHist transposed to block-major
//          [blk*NBMAX+u] so p1-write / p2-cursor-load are coalesced.
//      (3) flag2 -> dedup'd row list (atomicExch in l1fuse mark); l2fuse
//          runs off the dense list (no 1.2M flag reads / idle lanes).
//      (4) gemm 64x64 tile, 4x4/thread (k-ascending order: bitwise same).
// Predicted: bsort ~18, scanA ~1.5, p2 ~17, gemm ~6, l2 -2; total ~232.
// Falsification: total moves <6 us -> launch/fill overhead dominates ->
// R18 = cooperative mega-fusion of build chain, or declare gather floor.
//
// d_ws (4B units): embA bf16[totalF] | embB bf16[totalF] | Ub[B*64] |
//   Ib[B*64] | pairs int2[NB*CAP] | part int2[NB*CAP] | rowPtr[N] |
//   rowEnd[N] | blockHist[BP*NBMAX] | bucketTotal[NBMAX] |
//   flag2[N+1] ([N]=listCount) | list[N]   (~80 MB; 95 MB available)

#define EMB 64
#define BSZ 512         // rows per bucket (pow2: lr = r&511, u = r>>9)
#define NBMAX 512       // max buckets (actual: ceil(150000/512)=293)
#define BP 512          // partition blocks (edge segments)
#define CAP 7680        // static slots per bucket region (mean 6827 +10sd)

__device__ __forceinline__ float bf2f_lo(unsigned int u) {
    return __int_as_float((int)(u << 16));
}
__device__ __forceinline__ float bf2f_hi(unsigned int u) {
    return __int_as_float((int)(u & 0xFFFF0000u));
}
__device__ __forceinline__ float bf2f(unsigned short u) {
    return __int_as_float(((int)u) << 16);
}
__device__ __forceinline__ unsigned short f2bf(float f) {
    union { float f; unsigned int i; } v;
    v.f = f;
    unsigned int lsb = (v.i >> 16) & 1;
    v.i += 0x7fffu + lsb;          // round-to-nearest-even
    return (unsigned short)(v.i >> 16);
}
__device__ __forceinline__ unsigned int pack2(float a, float b) {
    return (unsigned int)f2bf(a) | ((unsigned int)f2bf(b) << 16);
}

// inclusive scan across a 64-lane wave (no barriers)
__device__ __forceinline__ int wave_iscan(int v) {
    int lane = threadIdx.x & 63;
#pragma unroll
    for (int off = 1; off < 64; off <<= 1) {
        int x = __shfl_up(v, off, 64);
        if (lane >= off) v += x;
    }
    return v;
}

// ---------- fused: init (concat->bf16, zero flag2+count) | p1 hist --------
// blocks [0, initBlocks): init; [initBlocks, initBlocks+BP): p1.
__global__ void ALGN_init_p1(const float4* __restrict__ ue, const float4* __restrict__ ie,
                             uint4* __restrict__ emb, int* __restrict__ flags, int nFlags,
                             int nUser8, int n8, int initBlocks,
                             const int* __restrict__ rows, int* __restrict__ blockHist,
                             int nE, int seg, int nBuckets) {
    __shared__ int h[NBMAX];
    if (blockIdx.x < initBlocks) {
        int t = blockIdx.x * blockDim.x + threadIdx.x;
        if (t < nFlags) flags[t] = 0;
        if (t >= n8) return;
        float4 a, b;
        if (t < nUser8) { a = ue[2 * t]; b = ue[2 * t + 1]; }
        else           { a = ie[2 * (t - nUser8)]; b = ie[2 * (t - nUser8) + 1]; }
        uint4 o;
        o.x = pack2(a.x, a.y);
        o.y = pack2(a.z, a.w);
        o.z = pack2(b.x, b.y);
        o.w = pack2(b.z, b.w);
        emb[t] = o;
    } else {
        int blk = blockIdx.x - initBlocks;
        for (int i = threadIdx.x; i < nBuckets; i += blockDim.x) h[i] = 0;
        __syncthreads();
        int beg = blk * seg, end = min(beg + seg, nE);
        for (int e = beg + threadIdx.x; e < end; e += blockDim.x)
            atomicAdd(&h[rows[e] >> 9], 1);
        __syncthreads();
        for (int u = threadIdx.x; u < nBuckets; u += blockDim.x)
            blockHist[blk * NBMAX + u] = h[u];   // block-major (coalesced)
    }
}

// ---------- scanA: per bucket, exclusive scan across BP=512 blocks --------
// blockDim = 256, 2 elements/thread; wave-shfl scan. Total -> bucketTotal.
// blockHist is block-major: element (blk,u) at [blk*NBMAX + u].
__global__ void ALGN_scanA(int* __restrict__ blockHist, int* __restrict__ bucketTotal) {
    __shared__ int wsum[4];
    int b = blockIdx.x, t = threadIdx.x;
    int wid = t >> 6;
    int v0 = blockHist[(2 * t) * NBMAX + b];
    int v1 = blockHist[(2 * t + 1) * NBMAX + b];
    int s = v0 + v1;
    int isc = wave_iscan(s);
    if ((t & 63) == 63) wsum[wid] = isc;
    __syncthreads();
    if (t < 64) {
        int x = (t < 4) ? wsum[t] : 0;
        x = wave_iscan(x);
        if (t < 4) wsum[t] = x;
    }
    __syncthreads();
    int incl = isc + ((wid > 0) ? wsum[wid - 1] : 0);
    int excl = incl - s;
    blockHist[(2 * t) * NBMAX + b]     = excl;   // exclusive over blocks
    blockHist[(2 * t + 1) * NBMAX + b] = excl + v0;
    if (t == 255) bucketTotal[b] = incl;
}

// ---------- partition pass 2: scatter packed records, LDS cursors ----------
// record: x = (localRow<<18) | col  (localRow<512, col<2^18), y = val bits
// Static bucket bases u*CAP. blk = XCD-grouped swizzle of blockIdx
// (adjacent segments -> same XCD L2 -> partial-line runs merge); 4 edges
// per thread, int4/float4 loads (seg x4-aligned).
__global__ void ALGN_p2(const int* __restrict__ rows, const int* __restrict__ cols,
                        const float* __restrict__ vals,
                        const int* __restrict__ blockHist,
                        int2* __restrict__ part, int nE, int seg, int nBuckets) {
    __shared__ int cur[NBMAX];
    int blk = ((blockIdx.x & 7) * (BP >> 3)) + (blockIdx.x >> 3);
    for (int u = threadIdx.x; u < nBuckets; u += blockDim.x)
        cur[u] = u * CAP + blockHist[blk * NBMAX + u];   // coalesced
    __syncthreads();
    int beg = blk * seg, end = min(beg + seg, nE);
    for (int e = beg + (threadIdx.x << 2); e < end; e += (blockDim.x << 2)) {
        if (e + 4 <= end) {
            int4   r = *(const int4*)(rows + e);
            int4   c = *(const int4*)(cols + e);
            float4 v = *(const float4*)(vals + e);
            int p0 = atomicAdd(&cur[r.x >> 9], 1);
            int p1 = atomicAdd(&cur[r.y >> 9], 1);
            int p2 = atomicAdd(&cur[r.z >> 9], 1);
            int p3 = atomicAdd(&cur[r.w >> 9], 1);
            part[p0] = make_int2(((r.x & 511) << 18) | c.x, __float_as_int(v.x));
            part[p1] = make_int2(((r.y & 511) << 18) | c.y, __float_as_int(v.y));
            part[p2] = make_int2(((r.z & 511) << 18) | c.z, __float_as_int(v.z));
            part[p3] = make_int2(((r.w & 511) << 18) | c.w, __float_as_int(v.w));
        } else {
            for (int k = e; k < end; ++k) {
                int rr = rows[k];
                int pos = atomicAdd(&cur[rr >> 9], 1);
                part[pos] = make_int2(((rr & 511) << 18) | cols[k], __float_as_int(vals[k]));
            }
        }
    }
}

// ---------- per-bucket counting sort (LDS-staged) -> rowPtr/rowEnd/pairs --
// blockDim = 1024. Stage bucket edges ONCE into LDS (<= CAP = 7680, 60 KB);
// hist + scatter passes read LDS. Static LDS total 62 KB < 64 KB cap.
__global__ void ALGN_bsort(const int2* __restrict__ part, const int* __restrict__ bucketTotal,
                           int2* __restrict__ pairs, int* __restrict__ rowPtr,
                           int* __restrict__ rowEnd, int nNodes) {
    __shared__ int2 ed[CAP];
    __shared__ int st[BSZ];
    __shared__ int wsum[8];
    int b = blockIdx.x, t = threadIdx.x;
    int base = b * CAP;
    int total = bucketTotal[b];
    for (int j = t; j < total; j += blockDim.x) ed[j] = part[base + j];
    if (t < BSZ) st[t] = 0;
    __syncthreads();
    for (int j = t; j < total; j += blockDim.x)
        atomicAdd(&st[ed[j].x >> 18], 1);
    __syncthreads();
    int wid = t >> 6;
    int v = (t < BSZ) ? st[t] : 0;
    int isc = wave_iscan(v);
    if ((t & 63) == 63 && wid < 8) wsum[wid] = isc;
    __syncthreads();
    if (t < 64) {
        int s = (t < 8) ? wsum[t] : 0;
        s = wave_iscan(s);
        if (t < 8) wsum[t] = s;
    }
    __syncthreads();
    int excl = isc - v + ((wid > 0 && wid < 8) ? wsum[wid - 1] : 0);
    __syncthreads();
    if (t < BSZ) st[t] = excl;                   // exclusive starts / cursors
    int row = b * BSZ + t;
    if (t < BSZ && row < nNodes) {
        rowPtr[row] = base + excl;
        rowEnd[row] = base + excl + v;
    }
    __syncthreads();
    for (int j = t; j < total; j += blockDim.x) {
        int2 p = ed[j];
        int lr = p.x >> 18;
        int pos = base + atomicAdd(&st[lr], 1);
        pairs[pos] = make_int2(p.x & 0x3FFFF, p.y);
    }
}

// ---------- SpMM row body: 8 lanes/row, uint4 = 8 bf16/lane, unroll x4 ----
// (R13-proven: 41 us, 32 VGPR, occ 61%; unroll-8 was flat at half occ.)
__device__ __forceinline__ void acc8(float& s0, float& s1, float& s2, float& s3,
                                     float& s4, float& s5, float& s6, float& s7,
                                     float v, uint4 x) {
    s0 += v * bf2f_lo(x.x); s1 += v * bf2f_hi(x.x);
    s2 += v * bf2f_lo(x.y); s3 += v * bf2f_hi(x.y);
    s4 += v * bf2f_lo(x.z); s5 += v * bf2f_hi(x.z);
    s6 += v * bf2f_lo(x.w); s7 += v * bf2f_hi(x.w);
}

__device__ __forceinline__ void spmm_row(const uint4* __restrict__ cur,
                                         uint4* __restrict__ next,
                                         const int* __restrict__ rowPtr,
                                         const int* __restrict__ rowEnd,
                                         const int2* __restrict__ pairs,
                                         int row, int fl) {
    int beg = rowPtr[row];
    int end = rowEnd[row];
    float s0 = 0.f, s1 = 0.f, s2 = 0.f, s3 = 0.f;
    float s4 = 0.f, s5 = 0.f, s6 = 0.f, s7 = 0.f;
    int j = beg;
    for (; j + 4 <= end; j += 4) {
        int2 e0 = pairs[j + 0];
        int2 e1 = pairs[j + 1];
        int2 e2 = pairs[j + 2];
        int2 e3 = pairs[j + 3];
        uint4 x0 = cur[(size_t)e0.x * 8 + fl];
        uint4 x1 = cur[(size_t)e1.x * 8 + fl];
        uint4 x2 = cur[(size_t)e2.x * 8 + fl];
        uint4 x3 = cur[(size_t)e3.x * 8 + fl];
        acc8(s0, s1, s2, s3, s4, s5, s6, s7, __int_as_float(e0.y), x0);
        acc8(s0, s1, s2, s3, s4, s5, s6, s7, __int_as_float(e1.y), x1);
        acc8(s0, s1, s2, s3, s4, s5, s6, s7, __int_as_float(e2.y), x2);
        acc8(s0, s1, s2, s3, s4, s5, s6, s7, __int_as_float(e3.y), x3);
    }
    for (; j < end; ++j) {
        int2 e = pairs[j];
        uint4 x = cur[(size_t)e.x * 8 + fl];
        acc8(s0, s1, s2, s3, s4, s5, s6, s7, __int_as_float(e.y), x);
    }
    uint4 o;
    o.x = pack2(s0, s1);
    o.y = pack2(s2, s3);
    o.z = pack2(s4, s5);
    o.w = pack2(s6, s7);
    next[(size_t)row * 8 + fl] = o;
}

// dedup'd flag + append to list
__device__ __forceinline__ void addFlag(int row, int* __restrict__ flag2,
                                        int* __restrict__ list, int* __restrict__ cnt) {
    if (atomicExch(&flag2[row], 1) == 0) {
        int p = atomicAdd(cnt, 1);
        list[p] = row;
    }
}

// ---------- fused layer 1: full spmm | mark2(list) | gather_set -----------
__global__ void ALGN_l1fuse(const uint4* __restrict__ curE, uint4* __restrict__ nextE,
                            const int* __restrict__ rowPtr, const int* __restrict__ rowEnd,
                            const int2* __restrict__ pairs, int nNodes, int spmmBlocks,
                            const int* __restrict__ users, const int* __restrict__ items,
                            int* __restrict__ flag2, int* __restrict__ list,
                            int* __restrict__ listCount,
                            int batch, int nUser, int markBlocks,
                            const unsigned short* __restrict__ emb0,
                            float* __restrict__ U, float* __restrict__ I) {
    if (blockIdx.x < spmmBlocks) {
        int tid = blockIdx.x * blockDim.x + threadIdx.x;
        int row = tid >> 3;
        int fl  = tid & 7;
        if (row >= nNodes) return;
        spmm_row(curE, nextE, rowPtr, rowEnd, pairs, row, fl);
    } else if (blockIdx.x < spmmBlocks + markBlocks) {
        int tid = (blockIdx.x - spmmBlocks) * blockDim.x + threadIdx.x;
        int idx = tid >> 4;
        int ln  = tid & 15;
        if (idx >= 2 * batch) return;
        int row = (idx < batch) ? users[idx] : (nUser + items[idx - batch]);
        if (ln == 0) addFlag(row, flag2, list, listCount);
        int beg = rowPtr[row], end = rowEnd[row];
        for (int j = beg + ln; j < end; j += 16)
            addFlag(pairs[j].x, flag2, list, listCount);
    } else {
        int t = (blockIdx.x - spmmBlocks - markBlocks) * blockDim.x + threadIdx.x;
        if (t >= batch * EMB) return;
        int b = t >> 6, c = t & 63;
        U[t] = bf2f(emb0[users[b] * EMB + c]) * 0.25f;
        I[t] = bf2f(emb0[(nUser + items[b]) * EMB + c]) * 0.25f;
    }
}

// ---------- fused layer 2: list spmm | gather_add(layer-1) ----------------
__global__ void ALGN_l2fuse(const uint4* __restrict__ curE, uint4* __restrict__ nextE,
                            const int* __restrict__ rowPtr, const int* __restrict__ rowEnd,
                            const int2* __restrict__ pairs,
                            const int* __restrict__ list, const int* __restrict__ listCount,
                            int spmmBlocks,
                            const unsigned short* __restrict__ embGA,
                            const int* __restrict__ users, const int* __restrict__ items,
                            float* __restrict__ U, float* __restrict__ I,
                            int batch, int nUser) {
    if (blockIdx.x < spmmBlocks) {
        int tid = blockIdx.x * blockDim.x + threadIdx.x;
        int li  = tid >> 3;
        int fl  = tid & 7;
        if (li >= *listCount) return;
        int row = list[li];
        spmm_row(curE, nextE, rowPtr, rowEnd, pairs, row, fl);
    } else {
        int t = (blockIdx.x - spmmBlocks) * blockDim.x + threadIdx.x;
        if (t >= batch * EMB) return;
        int b = t >> 6, c = t & 63;
        U[t] += bf2f(embGA[users[b] * EMB + c]) * 0.25f;
        I[t] += bf2f(embGA[(nUser + items[b]) * EMB + c]) * 0.25f;
    }
}

// ---------- fused layer 3: batch-list spmm | gather_add(layer-2) ----------
// Rows straight from users/items (dups write identical bytes: benign).
__global__ void ALGN_l3fuse(const uint4* __restrict__ curE, uint4* __restrict__ nextE,
                            const int* __restrict__ rowPtr, const int* __restrict__ rowEnd,
                            const int2* __restrict__ pairs,
                            const int* __restrict__ users, const int* __restrict__ items,
                            int batch, int nUser, int listBlocks,
                            const unsigned short* __restrict__ embGA,
                            float* __restrict__ U, float* __restrict__ I) {
    if (blockIdx.x < listBlocks) {
        int tid = blockIdx.x * blockDim.x + threadIdx.x;
        int idx = tid >> 3;
        int fl  = tid & 7;
        if (idx >= 2 * batch) return;
        int row = (idx < batch) ? users[idx] : (nUser + items[idx - batch]);
        spmm_row(curE, nextE, rowPtr, rowEnd, pairs, row, fl);
    } else {
        int t = (blockIdx.x - listBlocks) * blockDim.x + threadIdx.x;
        if (t >= batch * EMB) return;
        int b = t >> 6, c = t & 63;
        U[t] += bf2f(embGA[users[b] * EMB + c]) * 0.25f;
        I[t] += bf2f(embGA[(nUser + items[b]) * EMB + c]) * 0.25f;
    }
}

// ---------- sigmoid(U @ I^T): 64x64 tile, 256 threads, 4x4 out/thread -----
// Tile load fuses layer-3 gather_add (bitwise-identical f32 math).
// k-ascending accumulation: same sum order as the 32x32 version.
__global__ void ALGN_gemm_sigmoid(const float* __restrict__ U, const float* __restrict__ I,
                                  const unsigned short* __restrict__ embL3,
                                  const int* __restrict__ users, const int* __restrict__ items,
                                  float* __restrict__ out, int B, int nUser) {
    __shared__ float su[64][EMB + 1];
    __shared__ float si[64][EMB + 1];
    int tx = threadIdx.x, ty = threadIdx.y;     // 16x16
    int row0 = blockIdx.y * 64, col0 = blockIdx.x * 64;
    int tid = ty * 16 + tx;
    for (int k = tid; k < 64 * EMB; k += 256) {
        int r = k >> 6, c = k & 63;
        int ur = users[row0 + r];
        int ir = items[col0 + r];
        su[r][c] = U[(row0 + r) * EMB + c] + bf2f(embL3[ur * EMB + c]) * 0.25f;
        si[r][c] = I[(col0 + r) * EMB + c] + bf2f(embL3[(nUser + ir) * EMB + c]) * 0.25f;
    }
    __syncthreads();
    float acc[4][4] = {};
#pragma unroll
    for (int k = 0; k < EMB; ++k) {
        float a[4], bb[4];
#pragma unroll
        for (int i = 0; i < 4; ++i) a[i] = su[ty + 16 * i][k];
#pragma unroll
        for (int j = 0; j < 4; ++j) bb[j] = si[tx + 16 * j][k];
#pragma unroll
        for (int i = 0; i < 4; ++i)
#pragma unroll
            for (int j = 0; j < 4; ++j) acc[i][j] += a[i] * bb[j];
    }
#pragma unroll
    for (int i = 0; i < 4; ++i) {
        int r = row0 + ty + 16 * i;
#pragma unroll
        for (int j = 0; j < 4; ++j) {
            int c = col0 + tx + 16 * j;
            out[(size_t)r * B + c] = 1.f / (1.f + __expf(-acc[i][j]));
        }
    }
}

extern "C" void kernel_launch(void* const* d_in, const int* in_sizes, int n_in,
                              void* d_out, int out_size, void* d_ws, size_t ws_size,
                              hipStream_t stream) {
    const float* user_emb = (const float*)d_in[0];
    const float* item_emb = (const float*)d_in[1];
    const float* adj_vals = (const float*)d_in[2];
    const int*   adj_rows = (const int*)d_in[3];
    const int*   adj_cols = (const int*)d_in[4];
    const int*   users    = (const int*)d_in[5];
    const int*   items    = (const int*)d_in[6];
    float* out = (float*)d_out;

    const int nUserF = in_sizes[0];
    const int nItemF = in_sizes[1];
    const int nEdges = in_sizes[2];
    const int batch  = in_sizes[5];
    const int nUser  = nUserF / EMB;
    const int totalF = nUserF + nItemF;
    const int nNodes = totalF / EMB;
    const int n8     = totalF / 8;
    const int nBuckets = (nNodes + BSZ - 1) / BSZ;   // 293
    // seg rounded to x4 so p2's int4/float4 edge loads are 16B-aligned
    const int seg    = (((nEdges + BP - 1) / BP) + 3) & ~3;   // 3908

    unsigned short* embA = (unsigned short*)d_ws;
    unsigned short* embB = embA + totalF;
    float* Ub = (float*)(embB + totalF);
    float* Ib = Ub + (size_t)batch * EMB;
    int2*  pairs = (int2*)(Ib + (size_t)batch * EMB);
    int2*  part  = pairs + (size_t)nBuckets * CAP;
    int*   rowPtr = (int*)(part + (size_t)nBuckets * CAP);
    int*   rowEnd = rowPtr + nNodes;
    int*   blockHist   = rowEnd + nNodes;            // [BP*NBMAX], block-major
    int*   bucketTotal = blockHist + BP * NBMAX;
    int*   flag2 = bucketTotal + NBMAX;              // [nNodes+1]; [nNodes]=count
    int*   listCount = flag2 + nNodes;
    int*   list = listCount + 1;

    // ---- 1: fused init | p1 hist ----
    const int initBlocks = (n8 + 255) / 256;         // covers n8 and nNodes+1 flags
    ALGN_init_p1<<<initBlocks + BP, 256, 0, stream>>>(
        (const float4*)user_emb, (const float4*)item_emb, (uint4*)embA,
        flag2, nNodes + 1, nUserF / 8, n8, initBlocks,
        adj_rows, blockHist, nEdges, seg, nBuckets);

    // ---- 2: scanA (blockHist excl-over-blocks; bucketTotal) ----
    ALGN_scanA<<<nBuckets, 256, 0, stream>>>(blockHist, bucketTotal);

    // ---- 3: p2 scatter into static CAP regions ----
    ALGN_p2<<<BP, 256, 0, stream>>>(adj_rows, adj_cols, adj_vals,
                                    blockHist, part, nEdges, seg, nBuckets);

    // ---- 4: per-bucket LDS-staged counting sort -> rowPtr/rowEnd/pairs ----
    ALGN_bsort<<<nBuckets, 1024, 0, stream>>>(part, bucketTotal, pairs,
                                              rowPtr, rowEnd, nNodes);

    const int spmmBlocks = (nNodes * 8 + 255) / 256;
    const int markBlocks = (2 * batch * 16 + 255) / 256;
    const int gaBlocks   = (batch * EMB + 255) / 256;
    const int listBlocks = (2 * batch * 8 + 255) / 256;

    // ---- 5: layer-1 full spmm | mark2(list) | gather_set ----
    ALGN_l1fuse<<<spmmBlocks + markBlocks + gaBlocks, 256, 0, stream>>>(
        (const uint4*)embA, (uint4*)embB, rowPtr, rowEnd, pairs, nNodes, spmmBlocks,
        users, items, flag2, list, listCount, batch, nUser, markBlocks,
        embA, Ub, Ib);

    // ---- 6: layer-2 list spmm | gather_add(layer-1 = embB) ----
    ALGN_l2fuse<<<spmmBlocks + gaBlocks, 256, 0, stream>>>(
        (const uint4*)embB, (uint4*)embA, rowPtr, rowEnd, pairs,
        list, listCount, spmmBlocks, embB, users, items, Ub, Ib, batch, nUser);

    // ---- 7: layer-3 batch-list spmm | gather_add(layer-2 = embA) ----
    ALGN_l3fuse<<<listBlocks + gaBlocks, 256, 0, stream>>>(
        (const uint4*)embA, (uint4*)embB, rowPtr, rowEnd, pairs,
        users, items, batch, nUser, listBlocks,
        embA, Ub, Ib);

    // ---- 8: gemm + sigmoid with fused layer-3 gather_add ----
    dim3 gg(batch / 64, batch / 64);
    dim3 gb(16, 16);
    ALGN_gemm_sigmoid<<<gg, gb, 0, stream>>>(Ub, Ib, embB, users, items,
                                             out, batch, nUser);
}

// Round 6
// 250.028 us; speedup vs baseline: 1.0952x; 1.0952x over previous
//
#include <hip/hip_runtime.h>
#include <hip/hip_bf16.h>

// LightGCN on MI355X. R18: revert R17's list-append (single-counter atomic
// serialization); keep all other R17 mid-pipeline wins.
// R17 post-mortem: total 251.6 -> 273.8. l1fuse 42.1 -> 68.5 us with FETCH/
// WRITE UNCHANGED and VALUBusy 27 -> 17.6% -- not a traffic change, an issue
// -rate change. Only semantic diff in l1fuse: addFlag = atomicExch dedup +
// append via atomicAdd on ONE global counter. ~3-4K wave-coalesced
// same-line atomics ping-ponging across 8 XCDs ~= +26 us. Same failure
// family as R14's global cursors: single global serialization point fed by
// scattered producers. LESSON (3rd time): every producer must write to a
// location it owns by construction.
// Meanwhile non-l1fuse changes netted -4 us (bsort LDS-stage, BP=512 +
// block-major blockHist, 64^2 gemm, smaller scanA) -> KEEP those.
// R18 = R17 with mark back to plain flag2 stores; l2fuse flag-gated
// (R16-proven form).
// Predicted: l1fuse 68.5 -> ~42 (VALU ~27%, FETCH ~120 MB); total ~247.
// Falsification: l1fuse >= 50 -> cause was CAP=7680 pairs layout -> revert
// CAP to 8192 next round.
//
// d_ws (4B units): embA bf16[totalF] | embB bf16[totalF] | Ub[B*64] |
//   Ib[B*64] | pairs int2[NB*CAP] | part int2[NB*CAP] | rowPtr[N] |
//   rowEnd[N] | blockHist[BP*NBMAX] | bucketTotal[NBMAX] | flag2[N]
//   (~80 MB; 95 MB available)

#define EMB 64
#define BSZ 512         // rows per bucket (pow2: lr = r&511, u = r>>9)
#define NBMAX 512       // max buckets (actual: ceil(150000/512)=293)
#define BP 512          // partition blocks (edge segments)
#define CAP 7680        // static slots per bucket region (mean 6827 +10sd)

__device__ __forceinline__ float bf2f_lo(unsigned int u) {
    return __int_as_float((int)(u << 16));
}
__device__ __forceinline__ float bf2f_hi(unsigned int u) {
    return __int_as_float((int)(u & 0xFFFF0000u));
}
__device__ __forceinline__ float bf2f(unsigned short u) {
    return __int_as_float(((int)u) << 16);
}
__device__ __forceinline__ unsigned short f2bf(float f) {
    union { float f; unsigned int i; } v;
    v.f = f;
    unsigned int lsb = (v.i >> 16) & 1;
    v.i += 0x7fffu + lsb;          // round-to-nearest-even
    return (unsigned short)(v.i >> 16);
}
__device__ __forceinline__ unsigned int pack2(float a, float b) {
    return (unsigned int)f2bf(a) | ((unsigned int)f2bf(b) << 16);
}

// inclusive scan across a 64-lane wave (no barriers)
__device__ __forceinline__ int wave_iscan(int v) {
    int lane = threadIdx.x & 63;
#pragma unroll
    for (int off = 1; off < 64; off <<= 1) {
        int x = __shfl_up(v, off, 64);
        if (lane >= off) v += x;
    }
    return v;
}

// ---------- fused: init (concat->bf16, zero flag2) | p1 hist --------------
// blocks [0, initBlocks): init; [initBlocks, initBlocks+BP): p1.
__global__ void ALGN_init_p1(const float4* __restrict__ ue, const float4* __restrict__ ie,
                             uint4* __restrict__ emb, int* __restrict__ flags, int nFlags,
                             int nUser8, int n8, int initBlocks,
                             const int* __restrict__ rows, int* __restrict__ blockHist,
                             int nE, int seg, int nBuckets) {
    __shared__ int h[NBMAX];
    if (blockIdx.x < initBlocks) {
        int t = blockIdx.x * blockDim.x + threadIdx.x;
        if (t < nFlags) flags[t] = 0;
        if (t >= n8) return;
        float4 a, b;
        if (t < nUser8) { a = ue[2 * t]; b = ue[2 * t + 1]; }
        else           { a = ie[2 * (t - nUser8)]; b = ie[2 * (t - nUser8) + 1]; }
        uint4 o;
        o.x = pack2(a.x, a.y);
        o.y = pack2(a.z, a.w);
        o.z = pack2(b.x, b.y);
        o.w = pack2(b.z, b.w);
        emb[t] = o;
    } else {
        int blk = blockIdx.x - initBlocks;
        for (int i = threadIdx.x; i < nBuckets; i += blockDim.x) h[i] = 0;
        __syncthreads();
        int beg = blk * seg, end = min(beg + seg, nE);
        for (int e = beg + threadIdx.x; e < end; e += blockDim.x)
            atomicAdd(&h[rows[e] >> 9], 1);
        __syncthreads();
        for (int u = threadIdx.x; u < nBuckets; u += blockDim.x)
            blockHist[blk * NBMAX + u] = h[u];   // block-major (coalesced)
    }
}

// ---------- scanA: per bucket, exclusive scan across BP=512 blocks --------
// blockDim = 256, 2 elements/thread; wave-shfl scan. Total -> bucketTotal.
// blockHist is block-major: element (blk,u) at [blk*NBMAX + u].
__global__ void ALGN_scanA(int* __restrict__ blockHist, int* __restrict__ bucketTotal) {
    __shared__ int wsum[4];
    int b = blockIdx.x, t = threadIdx.x;
    int wid = t >> 6;
    int v0 = blockHist[(2 * t) * NBMAX + b];
    int v1 = blockHist[(2 * t + 1) * NBMAX + b];
    int s = v0 + v1;
    int isc = wave_iscan(s);
    if ((t & 63) == 63) wsum[wid] = isc;
    __syncthreads();
    if (t < 64) {
        int x = (t < 4) ? wsum[t] : 0;
        x = wave_iscan(x);
        if (t < 4) wsum[t] = x;
    }
    __syncthreads();
    int incl = isc + ((wid > 0) ? wsum[wid - 1] : 0);
    int excl = incl - s;
    blockHist[(2 * t) * NBMAX + b]     = excl;   // exclusive over blocks
    blockHist[(2 * t + 1) * NBMAX + b] = excl + v0;
    if (t == 255) bucketTotal[b] = incl;
}

// ---------- partition pass 2: scatter packed records, LDS cursors ----------
// record: x = (localRow<<18) | col  (localRow<512, col<2^18), y = val bits
// Static bucket bases u*CAP. blk = XCD-grouped swizzle of blockIdx
// (adjacent segments -> same XCD L2 -> partial-line runs merge); 4 edges
// per thread, int4/float4 loads (seg x4-aligned).
__global__ void ALGN_p2(const int* __restrict__ rows, const int* __restrict__ cols,
                        const float* __restrict__ vals,
                        const int* __restrict__ blockHist,
                        int2* __restrict__ part, int nE, int seg, int nBuckets) {
    __shared__ int cur[NBMAX];
    int blk = ((blockIdx.x & 7) * (BP >> 3)) + (blockIdx.x >> 3);
    for (int u = threadIdx.x; u < nBuckets; u += blockDim.x)
        cur[u] = u * CAP + blockHist[blk * NBMAX + u];   // coalesced
    __syncthreads();
    int beg = blk * seg, end = min(beg + seg, nE);
    for (int e = beg + (threadIdx.x << 2); e < end; e += (blockDim.x << 2)) {
        if (e + 4 <= end) {
            int4   r = *(const int4*)(rows + e);
            int4   c = *(const int4*)(cols + e);
            float4 v = *(const float4*)(vals + e);
            int p0 = atomicAdd(&cur[r.x >> 9], 1);
            int p1 = atomicAdd(&cur[r.y >> 9], 1);
            int p2 = atomicAdd(&cur[r.z >> 9], 1);
            int p3 = atomicAdd(&cur[r.w >> 9], 1);
            part[p0] = make_int2(((r.x & 511) << 18) | c.x, __float_as_int(v.x));
            part[p1] = make_int2(((r.y & 511) << 18) | c.y, __float_as_int(v.y));
            part[p2] = make_int2(((r.z & 511) << 18) | c.z, __float_as_int(v.z));
            part[p3] = make_int2(((r.w & 511) << 18) | c.w, __float_as_int(v.w));
        } else {
            for (int k = e; k < end; ++k) {
                int rr = rows[k];
                int pos = atomicAdd(&cur[rr >> 9], 1);
                part[pos] = make_int2(((rr & 511) << 18) | cols[k], __float_as_int(vals[k]));
            }
        }
    }
}

// ---------- per-bucket counting sort (LDS-staged) -> rowPtr/rowEnd/pairs --
// blockDim = 1024. Stage bucket edges ONCE into LDS (<= CAP = 7680, 60 KB);
// hist + scatter passes read LDS. Static LDS total 62 KB < 64 KB cap.
__global__ void ALGN_bsort(const int2* __restrict__ part, const int* __restrict__ bucketTotal,
                           int2* __restrict__ pairs, int* __restrict__ rowPtr,
                           int* __restrict__ rowEnd, int nNodes) {
    __shared__ int2 ed[CAP];
    __shared__ int st[BSZ];
    __shared__ int wsum[8];
    int b = blockIdx.x, t = threadIdx.x;
    int base = b * CAP;
    int total = bucketTotal[b];
    for (int j = t; j < total; j += blockDim.x) ed[j] = part[base + j];
    if (t < BSZ) st[t] = 0;
    __syncthreads();
    for (int j = t; j < total; j += blockDim.x)
        atomicAdd(&st[ed[j].x >> 18], 1);
    __syncthreads();
    int wid = t >> 6;
    int v = (t < BSZ) ? st[t] : 0;
    int isc = wave_iscan(v);
    if ((t & 63) == 63 && wid < 8) wsum[wid] = isc;
    __syncthreads();
    if (t < 64) {
        int s = (t < 8) ? wsum[t] : 0;
        s = wave_iscan(s);
        if (t < 8) wsum[t] = s;
    }
    __syncthreads();
    int excl = isc - v + ((wid > 0 && wid < 8) ? wsum[wid - 1] : 0);
    __syncthreads();
    if (t < BSZ) st[t] = excl;                   // exclusive starts / cursors
    int row = b * BSZ + t;
    if (t < BSZ && row < nNodes) {
        rowPtr[row] = base + excl;
        rowEnd[row] = base + excl + v;
    }
    __syncthreads();
    for (int j = t; j < total; j += blockDim.x) {
        int2 p = ed[j];
        int lr = p.x >> 18;
        int pos = base + atomicAdd(&st[lr], 1);
        pairs[pos] = make_int2(p.x & 0x3FFFF, p.y);
    }
}

// ---------- SpMM row body: 8 lanes/row, uint4 = 8 bf16/lane, unroll x4 ----
// (R13-proven: 41 us, 32 VGPR, occ 61%; unroll-8 was flat at half occ.)
__device__ __forceinline__ void acc8(float& s0, float& s1, float& s2, float& s3,
                                     float& s4, float& s5, float& s6, float& s7,
                                     float v, uint4 x) {
    s0 += v * bf2f_lo(x.x); s1 += v * bf2f_hi(x.x);
    s2 += v * bf2f_lo(x.y); s3 += v * bf2f_hi(x.y);
    s4 += v * bf2f_lo(x.z); s5 += v * bf2f_hi(x.z);
    s6 += v * bf2f_lo(x.w); s7 += v * bf2f_hi(x.w);
}

__device__ __forceinline__ void spmm_row(const uint4* __restrict__ cur,
                                         uint4* __restrict__ next,
                                         const int* __restrict__ rowPtr,
                                         const int* __restrict__ rowEnd,
                                         const int2* __restrict__ pairs,
                                         int row, int fl) {
    int beg = rowPtr[row];
    int end = rowEnd[row];
    float s0 = 0.f, s1 = 0.f, s2 = 0.f, s3 = 0.f;
    float s4 = 0.f, s5 = 0.f, s6 = 0.f, s7 = 0.f;
    int j = beg;
    for (; j + 4 <= end; j += 4) {
        int2 e0 = pairs[j + 0];
        int2 e1 = pairs[j + 1];
        int2 e2 = pairs[j + 2];
        int2 e3 = pairs[j + 3];
        uint4 x0 = cur[(size_t)e0.x * 8 + fl];
        uint4 x1 = cur[(size_t)e1.x * 8 + fl];
        uint4 x2 = cur[(size_t)e2.x * 8 + fl];
        uint4 x3 = cur[(size_t)e3.x * 8 + fl];
        acc8(s0, s1, s2, s3, s4, s5, s6, s7, __int_as_float(e0.y), x0);
        acc8(s0, s1, s2, s3, s4, s5, s6, s7, __int_as_float(e1.y), x1);
        acc8(s0, s1, s2, s3, s4, s5, s6, s7, __int_as_float(e2.y), x2);
        acc8(s0, s1, s2, s3, s4, s5, s6, s7, __int_as_float(e3.y), x3);
    }
    for (; j < end; ++j) {
        int2 e = pairs[j];
        uint4 x = cur[(size_t)e.x * 8 + fl];
        acc8(s0, s1, s2, s3, s4, s5, s6, s7, __int_as_float(e.y), x);
    }
    uint4 o;
    o.x = pack2(s0, s1);
    o.y = pack2(s2, s3);
    o.z = pack2(s4, s5);
    o.w = pack2(s6, s7);
    next[(size_t)row * 8 + fl] = o;
}

// ---------- fused layer 1: full spmm | mark2 (plain stores) | gather_set --
__global__ void ALGN_l1fuse(const uint4* __restrict__ curE, uint4* __restrict__ nextE,
                            const int* __restrict__ rowPtr, const int* __restrict__ rowEnd,
                            const int2* __restrict__ pairs, int nNodes, int spmmBlocks,
                            const int* __restrict__ users, const int* __restrict__ items,
                            int* __restrict__ flag2, int batch, int nUser, int markBlocks,
                            const unsigned short* __restrict__ emb0,
                            float* __restrict__ U, float* __restrict__ I) {
    if (blockIdx.x < spmmBlocks) {
        int tid = blockIdx.x * blockDim.x + threadIdx.x;
        int row = tid >> 3;
        int fl  = tid & 7;
        if (row >= nNodes) return;
        spmm_row(curE, nextE, rowPtr, rowEnd, pairs, row, fl);
    } else if (blockIdx.x < spmmBlocks + markBlocks) {
        int tid = (blockIdx.x - spmmBlocks) * blockDim.x + threadIdx.x;
        int idx = tid >> 4;
        int ln  = tid & 15;
        if (idx >= 2 * batch) return;
        int row = (idx < batch) ? users[idx] : (nUser + items[idx - batch]);
        if (ln == 0) flag2[row] = 1;
        int beg = rowPtr[row], end = rowEnd[row];
        for (int j = beg + ln; j < end; j += 16) flag2[pairs[j].x] = 1;
    } else {
        int t = (blockIdx.x - spmmBlocks - markBlocks) * blockDim.x + threadIdx.x;
        if (t >= batch * EMB) return;
        int b = t >> 6, c = t & 63;
        U[t] = bf2f(emb0[users[b] * EMB + c]) * 0.25f;
        I[t] = bf2f(emb0[(nUser + items[b]) * EMB + c]) * 0.25f;
    }
}

// ---------- fused layer 2: flag2 spmm | gather_add(layer-1) ---------------
__global__ void ALGN_l2fuse(const uint4* __restrict__ curE, uint4* __restrict__ nextE,
                            const int* __restrict__ rowPtr, const int* __restrict__ rowEnd,
                            const int2* __restrict__ pairs, const int* __restrict__ flag,
                            int nNodes, int spmmBlocks,
                            const unsigned short* __restrict__ embGA,
                            const int* __restrict__ users, const int* __restrict__ items,
                            float* __restrict__ U, float* __restrict__ I,
                            int batch, int nUser) {
    if (blockIdx.x < spmmBlocks) {
        int tid = blockIdx.x * blockDim.x + threadIdx.x;
        int row = tid >> 3;
        int fl  = tid & 7;
        if (row >= nNodes) return;
        if (!flag[row]) return;
        spmm_row(curE, nextE, rowPtr, rowEnd, pairs, row, fl);
    } else {
        int t = (blockIdx.x - spmmBlocks) * blockDim.x + threadIdx.x;
        if (t >= batch * EMB) return;
        int b = t >> 6, c = t & 63;
        U[t] += bf2f(embGA[users[b] * EMB + c]) * 0.25f;
        I[t] += bf2f(embGA[(nUser + items[b]) * EMB + c]) * 0.25f;
    }
}

// ---------- fused layer 3: batch-list spmm | gather_add(layer-2) ----------
// Rows straight from users/items (dups write identical bytes: benign).
__global__ void ALGN_l3fuse(const uint4* __restrict__ curE, uint4* __restrict__ nextE,
                            const int* __restrict__ rowPtr, const int* __restrict__ rowEnd,
                            const int2* __restrict__ pairs,
                            const int* __restrict__ users, const int* __restrict__ items,
                            int batch, int nUser, int listBlocks,
                            const unsigned short* __restrict__ embGA,
                            float* __restrict__ U, float* __restrict__ I) {
    if (blockIdx.x < listBlocks) {
        int tid = blockIdx.x * blockDim.x + threadIdx.x;
        int idx = tid >> 3;
        int fl  = tid & 7;
        if (idx >= 2 * batch) return;
        int row = (idx < batch) ? users[idx] : (nUser + items[idx - batch]);
        spmm_row(curE, nextE, rowPtr, rowEnd, pairs, row, fl);
    } else {
        int t = (blockIdx.x - listBlocks) * blockDim.x + threadIdx.x;
        if (t >= batch * EMB) return;
        int b = t >> 6, c = t & 63;
        U[t] += bf2f(embGA[users[b] * EMB + c]) * 0.25f;
        I[t] += bf2f(embGA[(nUser + items[b]) * EMB + c]) * 0.25f;
    }
}

// ---------- sigmoid(U @ I^T): 64x64 tile, 256 threads, 4x4 out/thread -----
// Tile load fuses layer-3 gather_add (bitwise-identical f32 math).
__global__ void ALGN_gemm_sigmoid(const float* __restrict__ U, const float* __restrict__ I,
                                  const unsigned short* __restrict__ embL3,
                                  const int* __restrict__ users, const int* __restrict__ items,
                                  float* __restrict__ out, int B, int nUser) {
    __shared__ float su[64][EMB + 1];
    __shared__ float si[64][EMB + 1];
    int tx = threadIdx.x, ty = threadIdx.y;     // 16x16
    int row0 = blockIdx.y * 64, col0 = blockIdx.x * 64;
    int tid = ty * 16 + tx;
    for (int k = tid; k < 64 * EMB; k += 256) {
        int r = k >> 6, c = k & 63;
        int ur = users[row0 + r];
        int ir = items[col0 + r];
        su[r][c] = U[(row0 + r) * EMB + c] + bf2f(embL3[ur * EMB + c]) * 0.25f;
        si[r][c] = I[(col0 + r) * EMB + c] + bf2f(embL3[(nUser + ir) * EMB + c]) * 0.25f;
    }
    __syncthreads();
    float acc[4][4] = {};
#pragma unroll
    for (int k = 0; k < EMB; ++k) {
        float a[4], bb[4];
#pragma unroll
        for (int i = 0; i < 4; ++i) a[i] = su[ty + 16 * i][k];
#pragma unroll
        for (int j = 0; j < 4; ++j) bb[j] = si[tx + 16 * j][k];
#pragma unroll
        for (int i = 0; i < 4; ++i)
#pragma unroll
            for (int j = 0; j < 4; ++j) acc[i][j] += a[i] * bb[j];
    }
#pragma unroll
    for (int i = 0; i < 4; ++i) {
        int r = row0 + ty + 16 * i;
#pragma unroll
        for (int j = 0; j < 4; ++j) {
            int c = col0 + tx + 16 * j;
            out[(size_t)r * B + c] = 1.f / (1.f + __expf(-acc[i][j]));
        }
    }
}

extern "C" void kernel_launch(void* const* d_in, const int* in_sizes, int n_in,
                              void* d_out, int out_size, void* d_ws, size_t ws_size,
                              hipStream_t stream) {
    const float* user_emb = (const float*)d_in[0];
    const float* item_emb = (const float*)d_in[1];
    const float* adj_vals = (const float*)d_in[2];
    const int*   adj_rows = (const int*)d_in[3];
    const int*   adj_cols = (const int*)d_in[4];
    const int*   users    = (const int*)d_in[5];
    const int*   items    = (const int*)d_in[6];
    float* out = (float*)d_out;

    const int nUserF = in_sizes[0];
    const int nItemF = in_sizes[1];
    const int nEdges = in_sizes[2];
    const int batch  = in_sizes[5];
    const int nUser  = nUserF / EMB;
    const int totalF = nUserF + nItemF;
    const int nNodes = totalF / EMB;
    const int n8     = totalF / 8;
    const int nBuckets = (nNodes + BSZ - 1) / BSZ;   // 293
    // seg rounded to x4 so p2's int4/float4 edge loads are 16B-aligned
    const int seg    = (((nEdges + BP - 1) / BP) + 3) & ~3;   // 3908

    unsigned short* embA = (unsigned short*)d_ws;
    unsigned short* embB = embA + totalF;
    float* Ub = (float*)(embB + totalF);
    float* Ib = Ub + (size_t)batch * EMB;
    int2*  pairs = (int2*)(Ib + (size_t)batch * EMB);
    int2*  part  = pairs + (size_t)nBuckets * CAP;
    int*   rowPtr = (int*)(part + (size_t)nBuckets * CAP);
    int*   rowEnd = rowPtr + nNodes;
    int*   blockHist   = rowEnd + nNodes;            // [BP*NBMAX], block-major
    int*   bucketTotal = blockHist + BP * NBMAX;
    int*   flag2 = bucketTotal + NBMAX;

    // ---- 1: fused init | p1 hist ----
    const int initBlocks = (n8 + 255) / 256;         // covers n8 and nNodes flags
    ALGN_init_p1<<<initBlocks + BP, 256, 0, stream>>>(
        (const float4*)user_emb, (const float4*)item_emb, (uint4*)embA,
        flag2, nNodes, nUserF / 8, n8, initBlocks,
        adj_rows, blockHist, nEdges, seg, nBuckets);

    // ---- 2: scanA (blockHist excl-over-blocks; bucketTotal) ----
    ALGN_scanA<<<nBuckets, 256, 0, stream>>>(blockHist, bucketTotal);

    // ---- 3: p2 scatter into static CAP regions ----
    ALGN_p2<<<BP, 256, 0, stream>>>(adj_rows, adj_cols, adj_vals,
                                    blockHist, part, nEdges, seg, nBuckets);

    // ---- 4: per-bucket LDS-staged counting sort -> rowPtr/rowEnd/pairs ----
    ALGN_bsort<<<nBuckets, 1024, 0, stream>>>(part, bucketTotal, pairs,
                                              rowPtr, rowEnd, nNodes);

    const int spmmBlocks = (nNodes * 8 + 255) / 256;
    const int markBlocks = (2 * batch * 16 + 255) / 256;
    const int gaBlocks   = (batch * EMB + 255) / 256;
    const int listBlocks = (2 * batch * 8 + 255) / 256;

    // ---- 5: layer-1 full spmm | mark2 | gather_set ----
    ALGN_l1fuse<<<spmmBlocks + markBlocks + gaBlocks, 256, 0, stream>>>(
        (const uint4*)embA, (uint4*)embB, rowPtr, rowEnd, pairs, nNodes, spmmBlocks,
        users, items, flag2, batch, nUser, markBlocks,
        embA, Ub, Ib);

    // ---- 6: layer-2 flag spmm | gather_add(layer-1 = embB) ----
    ALGN_l2fuse<<<spmmBlocks + gaBlocks, 256, 0, stream>>>(
        (const uint4*)embB, (uint4*)embA, rowPtr, rowEnd, pairs, flag2,
        nNodes, spmmBlocks, embB, users, items, Ub, Ib, batch, nUser);

    // ---- 7: layer-3 batch-list spmm | gather_add(layer-2 = embA) ----
    ALGN_l3fuse<<<listBlocks + gaBlocks, 256, 0, stream>>>(
        (const uint4*)embA, (uint4*)embB, rowPtr, rowEnd, pairs,
        users, items, batch, nUser, listBlocks,
        embA, Ub, Ib);

    // ---- 8: gemm + sigmoid with fused layer-3 gather_add ----
    dim3 gg(batch / 64, batch / 64);
    dim3 gb(16, 16);
    ALGN_gemm_sigmoid<<<gg, gb, 0, stream>>>(Ub, Ib, embB, users, items,
                                             out, batch, nUser);
}

// Round 8
// 247.784 us; speedup vs baseline: 1.1051x; 1.0091x over previous
//
#include <hip/hip_runtime.h>
#include <hip/hip_bf16.h>

// LightGCN on MI355X. R20: revert R19's cooperative build (container killer);
// R18 structure + bsort hist-fused staging (the one graph-safe R19 piece).
// R19 post-mortem: "container failed twice", no profile = launch-time abort.
// hipLaunchCooperativeKernel is NOT capturable into hip graphs on current
// ROCm; the bench graph-captures kernel_launch -> capture-illegal call
// aborts the container (same tripwire class as hipMalloc/hipDeviceSync).
// LESSON: no cooperative kernels under this harness. Stream dispatches only.
// R20 keeps: bsort hist pass fused into the LDS staging loop (intra-kernel,
// no launch semantics; saves a full 7680-entry LDS read pass per bucket).
// Predicted: R18 profile restored (l1fuse 42.2, FETCH ~121 MB, occ ~64%);
// bsort -2-3 us; total ~247-249 (R18 was 250.0).
// Standing ledger: l1fuse pinned at random-gather fabric ceiling (3.45 TB/s
// effective, occupancy-invariant, FETCH at per-XCD unique-line floor).
// Scattered producers must own their write slots (R14/R17 lessons).
// Next unprofiled suspect: l2fuse (~25-35 us est) -- R21 target.
//
// d_ws (4B units): embA bf16[totalF] | embB bf16[totalF] | Ub[B*64] |
//   Ib[B*64] | pairs int2[NB*CAP] | part int2[NB*CAP] | rowPtr[N] |
//   rowEnd[N] | blockHist[BP*NBMAX] | bucketTotal[NBMAX] | flag2[N]
//   (~80 MB; 95 MB available)

#define EMB 64
#define BSZ 512         // rows per bucket (pow2: lr = r&511, u = r>>9)
#define NBMAX 512       // max buckets (actual: ceil(150000/512)=293)
#define BP 512          // partition blocks (edge segments)
#define CAP 7680        // static slots per bucket region (mean 6827 +10sd)

__device__ __forceinline__ float bf2f_lo(unsigned int u) {
    return __int_as_float((int)(u << 16));
}
__device__ __forceinline__ float bf2f_hi(unsigned int u) {
    return __int_as_float((int)(u & 0xFFFF0000u));
}
__device__ __forceinline__ float bf2f(unsigned short u) {
    return __int_as_float(((int)u) << 16);
}
__device__ __forceinline__ unsigned short f2bf(float f) {
    union { float f; unsigned int i; } v;
    v.f = f;
    unsigned int lsb = (v.i >> 16) & 1;
    v.i += 0x7fffu + lsb;          // round-to-nearest-even
    return (unsigned short)(v.i >> 16);
}
__device__ __forceinline__ unsigned int pack2(float a, float b) {
    return (unsigned int)f2bf(a) | ((unsigned int)f2bf(b) << 16);
}

// inclusive scan across a 64-lane wave (no barriers)
__device__ __forceinline__ int wave_iscan(int v) {
    int lane = threadIdx.x & 63;
#pragma unroll
    for (int off = 1; off < 64; off <<= 1) {
        int x = __shfl_up(v, off, 64);
        if (lane >= off) v += x;
    }
    return v;
}

// ---------- fused: init (concat->bf16, zero flag2) | p1 hist --------------
// blocks [0, initBlocks): init; [initBlocks, initBlocks+BP): p1.
__global__ void ALGN_init_p1(const float4* __restrict__ ue, const float4* __restrict__ ie,
                             uint4* __restrict__ emb, int* __restrict__ flags, int nFlags,
                             int nUser8, int n8, int initBlocks,
                             const int* __restrict__ rows, int* __restrict__ blockHist,
                             int nE, int seg, int nBuckets) {
    __shared__ int h[NBMAX];
    if (blockIdx.x < initBlocks) {
        int t = blockIdx.x * blockDim.x + threadIdx.x;
        if (t < nFlags) flags[t] = 0;
        if (t >= n8) return;
        float4 a, b;
        if (t < nUser8) { a = ue[2 * t]; b = ue[2 * t + 1]; }
        else           { a = ie[2 * (t - nUser8)]; b = ie[2 * (t - nUser8) + 1]; }
        uint4 o;
        o.x = pack2(a.x, a.y);
        o.y = pack2(a.z, a.w);
        o.z = pack2(b.x, b.y);
        o.w = pack2(b.z, b.w);
        emb[t] = o;
    } else {
        int blk = blockIdx.x - initBlocks;
        for (int i = threadIdx.x; i < nBuckets; i += blockDim.x) h[i] = 0;
        __syncthreads();
        int beg = blk * seg, end = min(beg + seg, nE);
        for (int e = beg + threadIdx.x; e < end; e += blockDim.x)
            atomicAdd(&h[rows[e] >> 9], 1);
        __syncthreads();
        for (int u = threadIdx.x; u < nBuckets; u += blockDim.x)
            blockHist[blk * NBMAX + u] = h[u];   // block-major (coalesced)
    }
}

// ---------- scanA: per bucket, exclusive scan across BP=512 blocks --------
// blockDim = 256, 2 elements/thread; wave-shfl scan. Total -> bucketTotal.
// blockHist is block-major: element (blk,u) at [blk*NBMAX + u].
__global__ void ALGN_scanA(int* __restrict__ blockHist, int* __restrict__ bucketTotal) {
    __shared__ int wsum[4];
    int b = blockIdx.x, t = threadIdx.x;
    int wid = t >> 6;
    int v0 = blockHist[(2 * t) * NBMAX + b];
    int v1 = blockHist[(2 * t + 1) * NBMAX + b];
    int s = v0 + v1;
    int isc = wave_iscan(s);
    if ((t & 63) == 63) wsum[wid] = isc;
    __syncthreads();
    if (t < 64) {
        int x = (t < 4) ? wsum[t] : 0;
        x = wave_iscan(x);
        if (t < 4) wsum[t] = x;
    }
    __syncthreads();
    int incl = isc + ((wid > 0) ? wsum[wid - 1] : 0);
    int excl = incl - s;
    blockHist[(2 * t) * NBMAX + b]     = excl;   // exclusive over blocks
    blockHist[(2 * t + 1) * NBMAX + b] = excl + v0;
    if (t == 255) bucketTotal[b] = incl;
}

// ---------- partition pass 2: scatter packed records, LDS cursors ----------
// record: x = (localRow<<18) | col  (localRow<512, col<2^18), y = val bits
// Static bucket bases u*CAP. blk = XCD-grouped swizzle of blockIdx
// (adjacent segments -> same XCD L2 -> partial-line runs merge); 4 edges
// per thread, int4/float4 loads (seg x4-aligned).
__global__ void ALGN_p2(const int* __restrict__ rows, const int* __restrict__ cols,
                        const float* __restrict__ vals,
                        const int* __restrict__ blockHist,
                        int2* __restrict__ part, int nE, int seg, int nBuckets) {
    __shared__ int cur[NBMAX];
    int blk = ((blockIdx.x & 7) * (BP >> 3)) + (blockIdx.x >> 3);
    for (int u = threadIdx.x; u < nBuckets; u += blockDim.x)
        cur[u] = u * CAP + blockHist[blk * NBMAX + u];   // coalesced
    __syncthreads();
    int beg = blk * seg, end = min(beg + seg, nE);
    for (int e = beg + (threadIdx.x << 2); e < end; e += (blockDim.x << 2)) {
        if (e + 4 <= end) {
            int4   r = *(const int4*)(rows + e);
            int4   c = *(const int4*)(cols + e);
            float4 v = *(const float4*)(vals + e);
            int p0 = atomicAdd(&cur[r.x >> 9], 1);
            int p1 = atomicAdd(&cur[r.y >> 9], 1);
            int p2 = atomicAdd(&cur[r.z >> 9], 1);
            int p3 = atomicAdd(&cur[r.w >> 9], 1);
            part[p0] = make_int2(((r.x & 511) << 18) | c.x, __float_as_int(v.x));
            part[p1] = make_int2(((r.y & 511) << 18) | c.y, __float_as_int(v.y));
            part[p2] = make_int2(((r.z & 511) << 18) | c.z, __float_as_int(v.z));
            part[p3] = make_int2(((r.w & 511) << 18) | c.w, __float_as_int(v.w));
        } else {
            for (int k = e; k < end; ++k) {
                int rr = rows[k];
                int pos = atomicAdd(&cur[rr >> 9], 1);
                part[pos] = make_int2(((rr & 511) << 18) | cols[k], __float_as_int(vals[k]));
            }
        }
    }
}

// ---------- per-bucket counting sort (LDS-staged, hist fused into stage) --
// blockDim = 1024. Stage + hist in ONE pass; scan; rowPtr; scatter.
// Static LDS: ed 60 KB + st 2 KB < 64 KB cap.
__global__ void ALGN_bsort(const int2* __restrict__ part, const int* __restrict__ bucketTotal,
                           int2* __restrict__ pairs, int* __restrict__ rowPtr,
                           int* __restrict__ rowEnd, int nNodes) {
    __shared__ int2 ed[CAP];
    __shared__ int st[BSZ];
    __shared__ int wsum[8];
    int b = blockIdx.x, t = threadIdx.x;
    int base = b * CAP;
    int total = bucketTotal[b];
    if (t < BSZ) st[t] = 0;
    __syncthreads();
    for (int j = t; j < total; j += blockDim.x) {
        int2 p = part[base + j];
        ed[j] = p;
        atomicAdd(&st[p.x >> 18], 1);            // hist fused into staging
    }
    __syncthreads();
    int wid = t >> 6;
    int v = (t < BSZ) ? st[t] : 0;
    int isc = wave_iscan(v);
    if ((t & 63) == 63 && wid < 8) wsum[wid] = isc;
    __syncthreads();
    if (t < 64) {
        int s = (t < 8) ? wsum[t] : 0;
        s = wave_iscan(s);
        if (t < 8) wsum[t] = s;
    }
    __syncthreads();
    int excl = isc - v + ((wid > 0 && wid < 8) ? wsum[wid - 1] : 0);
    __syncthreads();
    if (t < BSZ) st[t] = excl;                   // exclusive starts / cursors
    int row = b * BSZ + t;
    if (t < BSZ && row < nNodes) {
        rowPtr[row] = base + excl;
        rowEnd[row] = base + excl + v;
    }
    __syncthreads();
    for (int j = t; j < total; j += blockDim.x) {
        int2 p = ed[j];
        int lr = p.x >> 18;
        int pos = base + atomicAdd(&st[lr], 1);
        pairs[pos] = make_int2(p.x & 0x3FFFF, p.y);
    }
}

// ---------- SpMM row body: 8 lanes/row, uint4 = 8 bf16/lane, unroll x4 ----
// (R13-proven: 41 us, 32 VGPR, occ 61%; unroll-8 was flat at half occ.)
__device__ __forceinline__ void acc8(float& s0, float& s1, float& s2, float& s3,
                                     float& s4, float& s5, float& s6, float& s7,
                                     float v, uint4 x) {
    s0 += v * bf2f_lo(x.x); s1 += v * bf2f_hi(x.x);
    s2 += v * bf2f_lo(x.y); s3 += v * bf2f_hi(x.y);
    s4 += v * bf2f_lo(x.z); s5 += v * bf2f_hi(x.z);
    s6 += v * bf2f_lo(x.w); s7 += v * bf2f_hi(x.w);
}

__device__ __forceinline__ void spmm_row(const uint4* __restrict__ cur,
                                         uint4* __restrict__ next,
                                         const int* __restrict__ rowPtr,
                                         const int* __restrict__ rowEnd,
                                         const int2* __restrict__ pairs,
                                         int row, int fl) {
    int beg = rowPtr[row];
    int end = rowEnd[row];
    float s0 = 0.f, s1 = 0.f, s2 = 0.f, s3 = 0.f;
    float s4 = 0.f, s5 = 0.f, s6 = 0.f, s7 = 0.f;
    int j = beg;
    for (; j + 4 <= end; j += 4) {
        int2 e0 = pairs[j + 0];
        int2 e1 = pairs[j + 1];
        int2 e2 = pairs[j + 2];
        int2 e3 = pairs[j + 3];
        uint4 x0 = cur[(size_t)e0.x * 8 + fl];
        uint4 x1 = cur[(size_t)e1.x * 8 + fl];
        uint4 x2 = cur[(size_t)e2.x * 8 + fl];
        uint4 x3 = cur[(size_t)e3.x * 8 + fl];
        acc8(s0, s1, s2, s3, s4, s5, s6, s7, __int_as_float(e0.y), x0);
        acc8(s0, s1, s2, s3, s4, s5, s6, s7, __int_as_float(e1.y), x1);
        acc8(s0, s1, s2, s3, s4, s5, s6, s7, __int_as_float(e2.y), x2);
        acc8(s0, s1, s2, s3, s4, s5, s6, s7, __int_as_float(e3.y), x3);
    }
    for (; j < end; ++j) {
        int2 e = pairs[j];
        uint4 x = cur[(size_t)e.x * 8 + fl];
        acc8(s0, s1, s2, s3, s4, s5, s6, s7, __int_as_float(e.y), x);
    }
    uint4 o;
    o.x = pack2(s0, s1);
    o.y = pack2(s2, s3);
    o.z = pack2(s4, s5);
    o.w = pack2(s6, s7);
    next[(size_t)row * 8 + fl] = o;
}

// ---------- fused layer 1: full spmm | mark2 (plain stores) | gather_set --
__global__ void ALGN_l1fuse(const uint4* __restrict__ curE, uint4* __restrict__ nextE,
                            const int* __restrict__ rowPtr, const int* __restrict__ rowEnd,
                            const int2* __restrict__ pairs, int nNodes, int spmmBlocks,
                            const int* __restrict__ users, const int* __restrict__ items,
                            int* __restrict__ flag2, int batch, int nUser, int markBlocks,
                            const unsigned short* __restrict__ emb0,
                            float* __restrict__ U, float* __restrict__ I) {
    if (blockIdx.x < spmmBlocks) {
        int tid = blockIdx.x * blockDim.x + threadIdx.x;
        int row = tid >> 3;
        int fl  = tid & 7;
        if (row >= nNodes) return;
        spmm_row(curE, nextE, rowPtr, rowEnd, pairs, row, fl);
    } else if (blockIdx.x < spmmBlocks + markBlocks) {
        int tid = (blockIdx.x - spmmBlocks) * blockDim.x + threadIdx.x;
        int idx = tid >> 4;
        int ln  = tid & 15;
        if (idx >= 2 * batch) return;
        int row = (idx < batch) ? users[idx] : (nUser + items[idx - batch]);
        if (ln == 0) flag2[row] = 1;
        int beg = rowPtr[row], end = rowEnd[row];
        for (int j = beg + ln; j < end; j += 16) flag2[pairs[j].x] = 1;
    } else {
        int t = (blockIdx.x - spmmBlocks - markBlocks) * blockDim.x + threadIdx.x;
        if (t >= batch * EMB) return;
        int b = t >> 6, c = t & 63;
        U[t] = bf2f(emb0[users[b] * EMB + c]) * 0.25f;
        I[t] = bf2f(emb0[(nUser + items[b]) * EMB + c]) * 0.25f;
    }
}

// ---------- fused layer 2: flag2 spmm | gather_add(layer-1) ---------------
__global__ void ALGN_l2fuse(const uint4* __restrict__ curE, uint4* __restrict__ nextE,
                            const int* __restrict__ rowPtr, const int* __restrict__ rowEnd,
                            const int2* __restrict__ pairs, const int* __restrict__ flag,
                            int nNodes, int spmmBlocks,
                            const unsigned short* __restrict__ embGA,
                            const int* __restrict__ users, const int* __restrict__ items,
                            float* __restrict__ U, float* __restrict__ I,
                            int batch, int nUser) {
    if (blockIdx.x < spmmBlocks) {
        int tid = blockIdx.x * blockDim.x + threadIdx.x;
        int row = tid >> 3;
        int fl  = tid & 7;
        if (row >= nNodes) return;
        if (!flag[row]) return;
        spmm_row(curE, nextE, rowPtr, rowEnd, pairs, row, fl);
    } else {
        int t = (blockIdx.x - spmmBlocks) * blockDim.x + threadIdx.x;
        if (t >= batch * EMB) return;
        int b = t >> 6, c = t & 63;
        U[t] += bf2f(embGA[users[b] * EMB + c]) * 0.25f;
        I[t] += bf2f(embGA[(nUser + items[b]) * EMB + c]) * 0.25f;
    }
}

// ---------- fused layer 3: batch-list spmm | gather_add(layer-2) ----------
// Rows straight from users/items (dups write identical bytes: benign).
__global__ void ALGN_l3fuse(const uint4* __restrict__ curE, uint4* __restrict__ nextE,
                            const int* __restrict__ rowPtr, const int* __restrict__ rowEnd,
                            const int2* __restrict__ pairs,
                            const int* __restrict__ users, const int* __restrict__ items,
                            int batch, int nUser, int listBlocks,
                            const unsigned short* __restrict__ embGA,
                            float* __restrict__ U, float* __restrict__ I) {
    if (blockIdx.x < listBlocks) {
        int tid = blockIdx.x * blockDim.x + threadIdx.x;
        int idx = tid >> 3;
        int fl  = tid & 7;
        if (idx >= 2 * batch) return;
        int row = (idx < batch) ? users[idx] : (nUser + items[idx - batch]);
        spmm_row(curE, nextE, rowPtr, rowEnd, pairs, row, fl);
    } else {
        int t = (blockIdx.x - listBlocks) * blockDim.x + threadIdx.x;
        if (t >= batch * EMB) return;
        int b = t >> 6, c = t & 63;
        U[t] += bf2f(embGA[users[b] * EMB + c]) * 0.25f;
        I[t] += bf2f(embGA[(nUser + items[b]) * EMB + c]) * 0.25f;
    }
}

// ---------- sigmoid(U @ I^T): 64x64 tile, 256 threads, 4x4 out/thread -----
// Tile load fuses layer-3 gather_add (bitwise-identical f32 math).
__global__ void ALGN_gemm_sigmoid(const float* __restrict__ U, const float* __restrict__ I,
                                  const unsigned short* __restrict__ embL3,
                                  const int* __restrict__ users, const int* __restrict__ items,
                                  float* __restrict__ out, int B, int nUser) {
    __shared__ float su[64][EMB + 1];
    __shared__ float si[64][EMB + 1];
    int tx = threadIdx.x, ty = threadIdx.y;     // 16x16
    int row0 = blockIdx.y * 64, col0 = blockIdx.x * 64;
    int tid = ty * 16 + tx;
    for (int k = tid; k < 64 * EMB; k += 256) {
        int r = k >> 6, c = k & 63;
        int ur = users[row0 + r];
        int ir = items[col0 + r];
        su[r][c] = U[(row0 + r) * EMB + c] + bf2f(embL3[ur * EMB + c]) * 0.25f;
        si[r][c] = I[(col0 + r) * EMB + c] + bf2f(embL3[(nUser + ir) * EMB + c]) * 0.25f;
    }
    __syncthreads();
    float acc[4][4] = {};
#pragma unroll
    for (int k = 0; k < EMB; ++k) {
        float a[4], bb[4];
#pragma unroll
        for (int i = 0; i < 4; ++i) a[i] = su[ty + 16 * i][k];
#pragma unroll
        for (int j = 0; j < 4; ++j) bb[j] = si[tx + 16 * j][k];
#pragma unroll
        for (int i = 0; i < 4; ++i)
#pragma unroll
            for (int j = 0; j < 4; ++j) acc[i][j] += a[i] * bb[j];
    }
#pragma unroll
    for (int i = 0; i < 4; ++i) {
        int r = row0 + ty + 16 * i;
#pragma unroll
        for (int j = 0; j < 4; ++j) {
            int c = col0 + tx + 16 * j;
            out[(size_t)r * B + c] = 1.f / (1.f + __expf(-acc[i][j]));
        }
    }
}

extern "C" void kernel_launch(void* const* d_in, const int* in_sizes, int n_in,
                              void* d_out, int out_size, void* d_ws, size_t ws_size,
                              hipStream_t stream) {
    const float* user_emb = (const float*)d_in[0];
    const float* item_emb = (const float*)d_in[1];
    const float* adj_vals = (const float*)d_in[2];
    const int*   adj_rows = (const int*)d_in[3];
    const int*   adj_cols = (const int*)d_in[4];
    const int*   users    = (const int*)d_in[5];
    const int*   items    = (const int*)d_in[6];
    float* out = (float*)d_out;

    const int nUserF = in_sizes[0];
    const int nItemF = in_sizes[1];
    const int nEdges = in_sizes[2];
    const int batch  = in_sizes[5];
    const int nUser  = nUserF / EMB;
    const int totalF = nUserF + nItemF;
    const int nNodes = totalF / EMB;
    const int n8     = totalF / 8;
    const int nBuckets = (nNodes + BSZ - 1) / BSZ;   // 293
    // seg rounded to x4 so p2's int4/float4 edge loads are 16B-aligned
    const int seg    = (((nEdges + BP - 1) / BP) + 3) & ~3;   // 3908

    unsigned short* embA = (unsigned short*)d_ws;
    unsigned short* embB = embA + totalF;
    float* Ub = (float*)(embB + totalF);
    float* Ib = Ub + (size_t)batch * EMB;
    int2*  pairs = (int2*)(Ib + (size_t)batch * EMB);
    int2*  part  = pairs + (size_t)nBuckets * CAP;
    int*   rowPtr = (int*)(part + (size_t)nBuckets * CAP);
    int*   rowEnd = rowPtr + nNodes;
    int*   blockHist   = rowEnd + nNodes;            // [BP*NBMAX], block-major
    int*   bucketTotal = blockHist + BP * NBMAX;
    int*   flag2 = bucketTotal + NBMAX;

    // ---- 1: fused init | p1 hist ----
    const int initBlocks = (n8 + 255) / 256;         // covers n8 and nNodes flags
    ALGN_init_p1<<<initBlocks + BP, 256, 0, stream>>>(
        (const float4*)user_emb, (const float4*)item_emb, (uint4*)embA,
        flag2, nNodes, nUserF / 8, n8, initBlocks,
        adj_rows, blockHist, nEdges, seg, nBuckets);

    // ---- 2: scanA (blockHist excl-over-blocks; bucketTotal) ----
    ALGN_scanA<<<nBuckets, 256, 0, stream>>>(blockHist, bucketTotal);

    // ---- 3: p2 scatter into static CAP regions ----
    ALGN_p2<<<BP, 256, 0, stream>>>(adj_rows, adj_cols, adj_vals,
                                    blockHist, part, nEdges, seg, nBuckets);

    // ---- 4: per-bucket LDS-staged counting sort -> rowPtr/rowEnd/pairs ----
    ALGN_bsort<<<nBuckets, 1024, 0, stream>>>(part, bucketTotal, pairs,
                                              rowPtr, rowEnd, nNodes);

    const int spmmBlocks = (nNodes * 8 + 255) / 256;
    const int markBlocks = (2 * batch * 16 + 255) / 256;
    const int gaBlocks   = (batch * EMB + 255) / 256;
    const int listBlocks = (2 * batch * 8 + 255) / 256;

    // ---- 5: layer-1 full spmm | mark2 | gather_set ----
    ALGN_l1fuse<<<spmmBlocks + markBlocks + gaBlocks, 256, 0, stream>>>(
        (const uint4*)embA, (uint4*)embB, rowPtr, rowEnd, pairs, nNodes, spmmBlocks,
        users, items, flag2, batch, nUser, markBlocks,
        embA, Ub, Ib);

    // ---- 6: layer-2 flag spmm | gather_add(layer-1 = embB) ----
    ALGN_l2fuse<<<spmmBlocks + gaBlocks, 256, 0, stream>>>(
        (const uint4*)embB, (uint4*)embA, rowPtr, rowEnd, pairs, flag2,
        nNodes, spmmBlocks, embB, users, items, Ub, Ib, batch, nUser);

    // ---- 7: layer-3 batch-list spmm | gather_add(layer-2 = embA) ----
    ALGN_l3fuse<<<listBlocks + gaBlocks, 256, 0, stream>>>(
        (const uint4*)embA, (uint4*)embB, rowPtr, rowEnd, pairs,
        users, items, batch, nUser, listBlocks,
        embA, Ub, Ib);

    // ---- 8: gemm + sigmoid with fused layer-3 gather_add ----
    dim3 gg(batch / 64, batch / 64);
    dim3 gb(16, 16);
    ALGN_gemm_sigmoid<<<gg, gb, 0, stream>>>(Ub, Ib, embB, users, items,
                                             out, batch, nUser);
}

// Round 9
// 247.023 us; speedup vs baseline: 1.1085x; 1.0031x over previous
//
#include <hip/hip_runtime.h>
#include <hip/hip_bf16.h>

// LightGCN on MI355X. R21: block-aggregated list compaction for l2fuse
// (R17's idea with the serialization bug fixed).
// R20 post-mortem: baseline restored at 247.8 (best); l1fuse 42.2 pinned at
// the random-gather fabric ceiling. Remaining: l2fuse (~20-25 us est) wastes
// waves -- 150K rows scanned, ~30% flagged, scattered -> ~96% of waves run
// the gather with most lanes idle.
// R17 failed because EACH new row did atomicAdd on ONE global counter
// (~50K serialized cross-XCD atomics = +26 us). R21 does the Guideline-12
// pattern: per-block LDS buffer (1024 slots; worst case 16 rows x deg<=~32
// ~= 528) + ONE atomicAdd per marking block (256 total) to reserve a
// contiguous chunk + block-owned writes. Producers own their slots by
// construction (R14/R17 lesson honored).
// l2fuse spmm runs off the packed list: ~45K rows -> ~5.6K fully-active
// waves vs ~18.7K divergent. Output bitwise identical (same row set).
// Predicted: l1fuse ~42.5 (noise); l2fuse -8..-12; total ~237-241.
// Falsification: total flat -> l2fuse was traffic-bound at its floor ->
// declare near-roofline next round (l1 pinned, fill untouchable).
//
// d_ws (4B units): embA bf16[totalF] | embB bf16[totalF] | Ub[B*64] |
//   Ib[B*64] | pairs int2[NB*CAP] | part int2[NB*CAP] | rowPtr[N] |
//   rowEnd[N] | blockHist[BP*NBMAX] | bucketTotal[NBMAX] |
//   flag2[N] | listCount[1] | list[N]   (~81 MB; 95 MB available)

#define EMB 64
#define BSZ 512         // rows per bucket (pow2: lr = r&511, u = r>>9)
#define NBMAX 512       // max buckets (actual: ceil(150000/512)=293)
#define BP 512          // partition blocks (edge segments)
#define CAP 7680        // static slots per bucket region (mean 6827 +10sd)
#define LBUF 1024       // per-block mark buffer (worst case ~528)

__device__ __forceinline__ float bf2f_lo(unsigned int u) {
    return __int_as_float((int)(u << 16));
}
__device__ __forceinline__ float bf2f_hi(unsigned int u) {
    return __int_as_float((int)(u & 0xFFFF0000u));
}
__device__ __forceinline__ float bf2f(unsigned short u) {
    return __int_as_float(((int)u) << 16);
}
__device__ __forceinline__ unsigned short f2bf(float f) {
    union { float f; unsigned int i; } v;
    v.f = f;
    unsigned int lsb = (v.i >> 16) & 1;
    v.i += 0x7fffu + lsb;          // round-to-nearest-even
    return (unsigned short)(v.i >> 16);
}
__device__ __forceinline__ unsigned int pack2(float a, float b) {
    return (unsigned int)f2bf(a) | ((unsigned int)f2bf(b) << 16);
}

// inclusive scan across a 64-lane wave (no barriers)
__device__ __forceinline__ int wave_iscan(int v) {
    int lane = threadIdx.x & 63;
#pragma unroll
    for (int off = 1; off < 64; off <<= 1) {
        int x = __shfl_up(v, off, 64);
        if (lane >= off) v += x;
    }
    return v;
}

// ---------- fused: init (concat->bf16, zero flag2+listCount) | p1 hist ----
// blocks [0, initBlocks): init; [initBlocks, initBlocks+BP): p1.
__global__ void ALGN_init_p1(const float4* __restrict__ ue, const float4* __restrict__ ie,
                             uint4* __restrict__ emb, int* __restrict__ flags, int nFlags,
                             int nUser8, int n8, int initBlocks,
                             const int* __restrict__ rows, int* __restrict__ blockHist,
                             int nE, int seg, int nBuckets) {
    __shared__ int h[NBMAX];
    if (blockIdx.x < initBlocks) {
        int t = blockIdx.x * blockDim.x + threadIdx.x;
        if (t < nFlags) flags[t] = 0;
        if (t >= n8) return;
        float4 a, b;
        if (t < nUser8) { a = ue[2 * t]; b = ue[2 * t + 1]; }
        else           { a = ie[2 * (t - nUser8)]; b = ie[2 * (t - nUser8) + 1]; }
        uint4 o;
        o.x = pack2(a.x, a.y);
        o.y = pack2(a.z, a.w);
        o.z = pack2(b.x, b.y);
        o.w = pack2(b.z, b.w);
        emb[t] = o;
    } else {
        int blk = blockIdx.x - initBlocks;
        for (int i = threadIdx.x; i < nBuckets; i += blockDim.x) h[i] = 0;
        __syncthreads();
        int beg = blk * seg, end = min(beg + seg, nE);
        for (int e = beg + threadIdx.x; e < end; e += blockDim.x)
            atomicAdd(&h[rows[e] >> 9], 1);
        __syncthreads();
        for (int u = threadIdx.x; u < nBuckets; u += blockDim.x)
            blockHist[blk * NBMAX + u] = h[u];   // block-major (coalesced)
    }
}

// ---------- scanA: per bucket, exclusive scan across BP=512 blocks --------
__global__ void ALGN_scanA(int* __restrict__ blockHist, int* __restrict__ bucketTotal) {
    __shared__ int wsum[4];
    int b = blockIdx.x, t = threadIdx.x;
    int wid = t >> 6;
    int v0 = blockHist[(2 * t) * NBMAX + b];
    int v1 = blockHist[(2 * t + 1) * NBMAX + b];
    int s = v0 + v1;
    int isc = wave_iscan(s);
    if ((t & 63) == 63) wsum[wid] = isc;
    __syncthreads();
    if (t < 64) {
        int x = (t < 4) ? wsum[t] : 0;
        x = wave_iscan(x);
        if (t < 4) wsum[t] = x;
    }
    __syncthreads();
    int incl = isc + ((wid > 0) ? wsum[wid - 1] : 0);
    int excl = incl - s;
    blockHist[(2 * t) * NBMAX + b]     = excl;   // exclusive over blocks
    blockHist[(2 * t + 1) * NBMAX + b] = excl + v0;
    if (t == 255) bucketTotal[b] = incl;
}

// ---------- partition pass 2: scatter packed records, LDS cursors ----------
__global__ void ALGN_p2(const int* __restrict__ rows, const int* __restrict__ cols,
                        const float* __restrict__ vals,
                        const int* __restrict__ blockHist,
                        int2* __restrict__ part, int nE, int seg, int nBuckets) {
    __shared__ int cur[NBMAX];
    int blk = ((blockIdx.x & 7) * (BP >> 3)) + (blockIdx.x >> 3);
    for (int u = threadIdx.x; u < nBuckets; u += blockDim.x)
        cur[u] = u * CAP + blockHist[blk * NBMAX + u];   // coalesced
    __syncthreads();
    int beg = blk * seg, end = min(beg + seg, nE);
    for (int e = beg + (threadIdx.x << 2); e < end; e += (blockDim.x << 2)) {
        if (e + 4 <= end) {
            int4   r = *(const int4*)(rows + e);
            int4   c = *(const int4*)(cols + e);
            float4 v = *(const float4*)(vals + e);
            int p0 = atomicAdd(&cur[r.x >> 9], 1);
            int p1 = atomicAdd(&cur[r.y >> 9], 1);
            int p2 = atomicAdd(&cur[r.z >> 9], 1);
            int p3 = atomicAdd(&cur[r.w >> 9], 1);
            part[p0] = make_int2(((r.x & 511) << 18) | c.x, __float_as_int(v.x));
            part[p1] = make_int2(((r.y & 511) << 18) | c.y, __float_as_int(v.y));
            part[p2] = make_int2(((r.z & 511) << 18) | c.z, __float_as_int(v.z));
            part[p3] = make_int2(((r.w & 511) << 18) | c.w, __float_as_int(v.w));
        } else {
            for (int k = e; k < end; ++k) {
                int rr = rows[k];
                int pos = atomicAdd(&cur[rr >> 9], 1);
                part[pos] = make_int2(((rr & 511) << 18) | cols[k], __float_as_int(vals[k]));
            }
        }
    }
}

// ---------- per-bucket counting sort (LDS-staged, hist fused into stage) --
__global__ void ALGN_bsort(const int2* __restrict__ part, const int* __restrict__ bucketTotal,
                           int2* __restrict__ pairs, int* __restrict__ rowPtr,
                           int* __restrict__ rowEnd, int nNodes) {
    __shared__ int2 ed[CAP];
    __shared__ int st[BSZ];
    __shared__ int wsum[8];
    int b = blockIdx.x, t = threadIdx.x;
    int base = b * CAP;
    int total = bucketTotal[b];
    if (t < BSZ) st[t] = 0;
    __syncthreads();
    for (int j = t; j < total; j += blockDim.x) {
        int2 p = part[base + j];
        ed[j] = p;
        atomicAdd(&st[p.x >> 18], 1);            // hist fused into staging
    }
    __syncthreads();
    int wid = t >> 6;
    int v = (t < BSZ) ? st[t] : 0;
    int isc = wave_iscan(v);
    if ((t & 63) == 63 && wid < 8) wsum[wid] = isc;
    __syncthreads();
    if (t < 64) {
        int s = (t < 8) ? wsum[t] : 0;
        s = wave_iscan(s);
        if (t < 8) wsum[t] = s;
    }
    __syncthreads();
    int excl = isc - v + ((wid > 0 && wid < 8) ? wsum[wid - 1] : 0);
    __syncthreads();
    if (t < BSZ) st[t] = excl;                   // exclusive starts / cursors
    int row = b * BSZ + t;
    if (t < BSZ && row < nNodes) {
        rowPtr[row] = base + excl;
        rowEnd[row] = base + excl + v;
    }
    __syncthreads();
    for (int j = t; j < total; j += blockDim.x) {
        int2 p = ed[j];
        int lr = p.x >> 18;
        int pos = base + atomicAdd(&st[lr], 1);
        pairs[pos] = make_int2(p.x & 0x3FFFF, p.y);
    }
}

// ---------- SpMM row body: 8 lanes/row, uint4 = 8 bf16/lane, unroll x4 ----
__device__ __forceinline__ void acc8(float& s0, float& s1, float& s2, float& s3,
                                     float& s4, float& s5, float& s6, float& s7,
                                     float v, uint4 x) {
    s0 += v * bf2f_lo(x.x); s1 += v * bf2f_hi(x.x);
    s2 += v * bf2f_lo(x.y); s3 += v * bf2f_hi(x.y);
    s4 += v * bf2f_lo(x.z); s5 += v * bf2f_hi(x.z);
    s6 += v * bf2f_lo(x.w); s7 += v * bf2f_hi(x.w);
}

__device__ __forceinline__ void spmm_row(const uint4* __restrict__ cur,
                                         uint4* __restrict__ next,
                                         const int* __restrict__ rowPtr,
                                         const int* __restrict__ rowEnd,
                                         const int2* __restrict__ pairs,
                                         int row, int fl) {
    int beg = rowPtr[row];
    int end = rowEnd[row];
    float s0 = 0.f, s1 = 0.f, s2 = 0.f, s3 = 0.f;
    float s4 = 0.f, s5 = 0.f, s6 = 0.f, s7 = 0.f;
    int j = beg;
    for (; j + 4 <= end; j += 4) {
        int2 e0 = pairs[j + 0];
        int2 e1 = pairs[j + 1];
        int2 e2 = pairs[j + 2];
        int2 e3 = pairs[j + 3];
        uint4 x0 = cur[(size_t)e0.x * 8 + fl];
        uint4 x1 = cur[(size_t)e1.x * 8 + fl];
        uint4 x2 = cur[(size_t)e2.x * 8 + fl];
        uint4 x3 = cur[(size_t)e3.x * 8 + fl];
        acc8(s0, s1, s2, s3, s4, s5, s6, s7, __int_as_float(e0.y), x0);
        acc8(s0, s1, s2, s3, s4, s5, s6, s7, __int_as_float(e1.y), x1);
        acc8(s0, s1, s2, s3, s4, s5, s6, s7, __int_as_float(e2.y), x2);
        acc8(s0, s1, s2, s3, s4, s5, s6, s7, __int_as_float(e3.y), x3);
    }
    for (; j < end; ++j) {
        int2 e = pairs[j];
        uint4 x = cur[(size_t)e.x * 8 + fl];
        acc8(s0, s1, s2, s3, s4, s5, s6, s7, __int_as_float(e.y), x);
    }
    uint4 o;
    o.x = pack2(s0, s1);
    o.y = pack2(s2, s3);
    o.z = pack2(s4, s5);
    o.w = pack2(s6, s7);
    next[(size_t)row * 8 + fl] = o;
}

// dedup mark + block-local buffer append (overflow: direct global, rare)
__device__ __forceinline__ void markRow(int row, int* __restrict__ flag2,
                                        int* lbuf, int* lcnt,
                                        int* __restrict__ list, int* __restrict__ listCount) {
    if (atomicExch(&flag2[row], 1) == 0) {
        int p = atomicAdd(lcnt, 1);
        if (p < LBUF) lbuf[p] = row;
        else { int g = atomicAdd(listCount, 1); list[g] = row; }
    }
}

// ---------- fused layer 1: full spmm | mark2(block-agg list) | gather_set --
__global__ void ALGN_l1fuse(const uint4* __restrict__ curE, uint4* __restrict__ nextE,
                            const int* __restrict__ rowPtr, const int* __restrict__ rowEnd,
                            const int2* __restrict__ pairs, int nNodes, int spmmBlocks,
                            const int* __restrict__ users, const int* __restrict__ items,
                            int* __restrict__ flag2, int* __restrict__ list,
                            int* __restrict__ listCount,
                            int batch, int nUser, int markBlocks,
                            const unsigned short* __restrict__ emb0,
                            float* __restrict__ U, float* __restrict__ I) {
    if (blockIdx.x < spmmBlocks) {
        int tid = blockIdx.x * blockDim.x + threadIdx.x;
        int row = tid >> 3;
        int fl  = tid & 7;
        if (row >= nNodes) return;
        spmm_row(curE, nextE, rowPtr, rowEnd, pairs, row, fl);
    } else if (blockIdx.x < spmmBlocks + markBlocks) {
        __shared__ int lbuf[LBUF];
        __shared__ int lcnt, lbase;
        if (threadIdx.x == 0) lcnt = 0;
        __syncthreads();
        int tid = (blockIdx.x - spmmBlocks) * blockDim.x + threadIdx.x;
        int idx = tid >> 4;
        int ln  = tid & 15;
        if (idx < 2 * batch) {
            int row = (idx < batch) ? users[idx] : (nUser + items[idx - batch]);
            if (ln == 0) markRow(row, flag2, lbuf, &lcnt, list, listCount);
            int beg = rowPtr[row], end = rowEnd[row];
            for (int j = beg + ln; j < end; j += 16)
                markRow(pairs[j].x, flag2, lbuf, &lcnt, list, listCount);
        }
        __syncthreads();
        int n = min(lcnt, LBUF);
        if (threadIdx.x == 0) lbase = atomicAdd(listCount, n);   // ONE per block
        __syncthreads();
        for (int i = threadIdx.x; i < n; i += blockDim.x) list[lbase + i] = lbuf[i];
    } else {
        int t = (blockIdx.x - spmmBlocks - markBlocks) * blockDim.x + threadIdx.x;
        if (t >= batch * EMB) return;
        int b = t >> 6, c = t & 63;
        U[t] = bf2f(emb0[users[b] * EMB + c]) * 0.25f;
        I[t] = bf2f(emb0[(nUser + items[b]) * EMB + c]) * 0.25f;
    }
}

// ---------- fused layer 2: packed-list spmm | gather_add(layer-1) ---------
__global__ void ALGN_l2fuse(const uint4* __restrict__ curE, uint4* __restrict__ nextE,
                            const int* __restrict__ rowPtr, const int* __restrict__ rowEnd,
                            const int2* __restrict__ pairs,
                            const int* __restrict__ list, const int* __restrict__ listCount,
                            int spmmBlocks,
                            const unsigned short* __restrict__ embGA,
                            const int* __restrict__ users, const int* __restrict__ items,
                            float* __restrict__ U, float* __restrict__ I,
                            int batch, int nUser) {
    if (blockIdx.x < spmmBlocks) {
        int tid = blockIdx.x * blockDim.x + threadIdx.x;
        int li  = tid >> 3;
        int fl  = tid & 7;
        if (li >= *listCount) return;    // same-address load: L2 broadcast
        spmm_row(curE, nextE, rowPtr, rowEnd, pairs, list[li], fl);
    } else {
        int t = (blockIdx.x - spmmBlocks) * blockDim.x + threadIdx.x;
        if (t >= batch * EMB) return;
        int b = t >> 6, c = t & 63;
        U[t] += bf2f(embGA[users[b] * EMB + c]) * 0.25f;
        I[t] += bf2f(embGA[(nUser + items[b]) * EMB + c]) * 0.25f;
    }
}

// ---------- fused layer 3: batch-list spmm | gather_add(layer-2) ----------
__global__ void ALGN_l3fuse(const uint4* __restrict__ curE, uint4* __restrict__ nextE,
                            const int* __restrict__ rowPtr, const int* __restrict__ rowEnd,
                            const int2* __restrict__ pairs,
                            const int* __restrict__ users, const int* __restrict__ items,
                            int batch, int nUser, int listBlocks,
                            const unsigned short* __restrict__ embGA,
                            float* __restrict__ U, float* __restrict__ I) {
    if (blockIdx.x < listBlocks) {
        int tid = blockIdx.x * blockDim.x + threadIdx.x;
        int idx = tid >> 3;
        int fl  = tid & 7;
        if (idx >= 2 * batch) return;
        int row = (idx < batch) ? users[idx] : (nUser + items[idx - batch]);
        spmm_row(curE, nextE, rowPtr, rowEnd, pairs, row, fl);
    } else {
        int t = (blockIdx.x - listBlocks) * blockDim.x + threadIdx.x;
        if (t >= batch * EMB) return;
        int b = t >> 6, c = t & 63;
        U[t] += bf2f(embGA[users[b] * EMB + c]) * 0.25f;
        I[t] += bf2f(embGA[(nUser + items[b]) * EMB + c]) * 0.25f;
    }
}

// ---------- sigmoid(U @ I^T): 64x64 tile, 256 threads, 4x4 out/thread -----
__global__ void ALGN_gemm_sigmoid(const float* __restrict__ U, const float* __restrict__ I,
                                  const unsigned short* __restrict__ embL3,
                                  const int* __restrict__ users, const int* __restrict__ items,
                                  float* __restrict__ out, int B, int nUser) {
    __shared__ float su[64][EMB + 1];
    __shared__ float si[64][EMB + 1];
    int tx = threadIdx.x, ty = threadIdx.y;     // 16x16
    int row0 = blockIdx.y * 64, col0 = blockIdx.x * 64;
    int tid = ty * 16 + tx;
    for (int k = tid; k < 64 * EMB; k += 256) {
        int r = k >> 6, c = k & 63;
        int ur = users[row0 + r];
        int ir = items[col0 + r];
        su[r][c] = U[(row0 + r) * EMB + c] + bf2f(embL3[ur * EMB + c]) * 0.25f;
        si[r][c] = I[(col0 + r) * EMB + c] + bf2f(embL3[(nUser + ir) * EMB + c]) * 0.25f;
    }
    __syncthreads();
    float acc[4][4] = {};
#pragma unroll
    for (int k = 0; k < EMB; ++k) {
        float a[4], bb[4];
#pragma unroll
        for (int i = 0; i < 4; ++i) a[i] = su[ty + 16 * i][k];
#pragma unroll
        for (int j = 0; j < 4; ++j) bb[j] = si[tx + 16 * j][k];
#pragma unroll
        for (int i = 0; i < 4; ++i)
#pragma unroll
            for (int j = 0; j < 4; ++j) acc[i][j] += a[i] * bb[j];
    }
#pragma unroll
    for (int i = 0; i < 4; ++i) {
        int r = row0 + ty + 16 * i;
#pragma unroll
        for (int j = 0; j < 4; ++j) {
            int c = col0 + tx + 16 * j;
            out[(size_t)r * B + c] = 1.f / (1.f + __expf(-acc[i][j]));
        }
    }
}

extern "C" void kernel_launch(void* const* d_in, const int* in_sizes, int n_in,
                              void* d_out, int out_size, void* d_ws, size_t ws_size,
                              hipStream_t stream) {
    const float* user_emb = (const float*)d_in[0];
    const float* item_emb = (const float*)d_in[1];
    const float* adj_vals = (const float*)d_in[2];
    const int*   adj_rows = (const int*)d_in[3];
    const int*   adj_cols = (const int*)d_in[4];
    const int*   users    = (const int*)d_in[5];
    const int*   items    = (const int*)d_in[6];
    float* out = (float*)d_out;

    const int nUserF = in_sizes[0];
    const int nItemF = in_sizes[1];
    const int nEdges = in_sizes[2];
    const int batch  = in_sizes[5];
    const int nUser  = nUserF / EMB;
    const int totalF = nUserF + nItemF;
    const int nNodes = totalF / EMB;
    const int n8     = totalF / 8;
    const int nBuckets = (nNodes + BSZ - 1) / BSZ;   // 293
    // seg rounded to x4 so p2's int4/float4 edge loads are 16B-aligned
    const int seg    = (((nEdges + BP - 1) / BP) + 3) & ~3;   // 3908

    unsigned short* embA = (unsigned short*)d_ws;
    unsigned short* embB = embA + totalF;
    float* Ub = (float*)(embB + totalF);
    float* Ib = Ub + (size_t)batch * EMB;
    int2*  pairs = (int2*)(Ib + (size_t)batch * EMB);
    int2*  part  = pairs + (size_t)nBuckets * CAP;
    int*   rowPtr = (int*)(part + (size_t)nBuckets * CAP);
    int*   rowEnd = rowPtr + nNodes;
    int*   blockHist   = rowEnd + nNodes;            // [BP*NBMAX], block-major
    int*   bucketTotal = blockHist + BP * NBMAX;
    int*   flag2 = bucketTotal + NBMAX;              // [nNodes]
    int*   listCount = flag2 + nNodes;               // [1]
    int*   list = listCount + 1;                     // [nNodes]

    // ---- 1: fused init | p1 hist (zeroes flag2 AND listCount) ----
    const int initBlocks = (n8 + 255) / 256;         // n8 = 18750 >= nNodes+1
    ALGN_init_p1<<<initBlocks + BP, 256, 0, stream>>>(
        (const float4*)user_emb, (const float4*)item_emb, (uint4*)embA,
        flag2, nNodes + 1, nUserF / 8, n8, initBlocks,
        adj_rows, blockHist, nEdges, seg, nBuckets);

    // ---- 2: scanA (blockHist excl-over-blocks; bucketTotal) ----
    ALGN_scanA<<<nBuckets, 256, 0, stream>>>(blockHist, bucketTotal);

    // ---- 3: p2 scatter into static CAP regions ----
    ALGN_p2<<<BP, 256, 0, stream>>>(adj_rows, adj_cols, adj_vals,
                                    blockHist, part, nEdges, seg, nBuckets);

    // ---- 4: per-bucket LDS-staged counting sort -> rowPtr/rowEnd/pairs ----
    ALGN_bsort<<<nBuckets, 1024, 0, stream>>>(part, bucketTotal, pairs,
                                              rowPtr, rowEnd, nNodes);

    const int spmmBlocks = (nNodes * 8 + 255) / 256;
    const int markBlocks = (2 * batch * 16 + 255) / 256;
    const int gaBlocks   = (batch * EMB + 255) / 256;
    const int listBlocks = (2 * batch * 8 + 255) / 256;

    // ---- 5: layer-1 full spmm | mark2(block-agg list) | gather_set ----
    ALGN_l1fuse<<<spmmBlocks + markBlocks + gaBlocks, 256, 0, stream>>>(
        (const uint4*)embA, (uint4*)embB, rowPtr, rowEnd, pairs, nNodes, spmmBlocks,
        users, items, flag2, list, listCount, batch, nUser, markBlocks,
        embA, Ub, Ib);

    // ---- 6: layer-2 packed-list spmm | gather_add(layer-1 = embB) ----
    ALGN_l2fuse<<<spmmBlocks + gaBlocks, 256, 0, stream>>>(
        (const uint4*)embB, (uint4*)embA, rowPtr, rowEnd, pairs,
        list, listCount, spmmBlocks, embB, users, items, Ub, Ib, batch, nUser);

    // ---- 7: layer-3 batch-list spmm | gather_add(layer-2 = embA) ----
    ALGN_l3fuse<<<listBlocks + gaBlocks, 256, 0, stream>>>(
        (const uint4*)embA, (uint4*)embB, rowPtr, rowEnd, pairs,
        users, items, batch, nUser, listBlocks,
        embA, Ub, Ib);

    // ---- 8: gemm + sigmoid with fused layer-3 gather_add ----
    dim3 gg(batch / 64, batch / 64);
    dim3 gb(16, 16);
    ALGN_gemm_sigmoid<<<gg, gb, 0, stream>>>(Ub, Ib, embB, users, items,
                                             out, batch, nUser);
}